// Round 18
// baseline (102.453 us; speedup 1.0000x reference)
//
#include <hip/hip_runtime.h>
#include <hip/hip_bf16.h>
#include <cstdint>

// Problem constants (B=2, H=16 -> 32 heads)
#define LQ_N   2048
#define LK_N   2048
#define DD     128
#define NHEADS 32
#define QBLK   128               // q rows per block (4 waves x 32 rows)
#define KVBLK  64
#define NKV    (LK_N / KVBLK)    // 32 kv tiles
#define NQB    (LQ_N / QBLK)     // 16 q blocks
#define SCALE  0.08838834764831845f            // 1/sqrt(128)
#define SCALE2 0.1275525003267101f             // SCALE * log2(e)

// ws layout: [K tiles][V^T tiles], granule-transposed (R5-verified, conflict-free)
#define KTILE_BYTES (KVBLK * DD * 2)                        // 16 KiB per tile
#define WS_K_BYTES  ((size_t)NHEADS * NKV * KTILE_BYTES)    // 16 MiB
#define WS_NEED     (2 * WS_K_BYTES)                        // 32 MiB

// main-kernel dynamic LDS: K ring x3 + V ring x2 = 80 KiB -> 2 blocks/CU
#define KB_OFF(s)  ((size_t)(s) * KTILE_BYTES)
#define VB_OFF(s)  ((size_t)(3 + (s)) * KTILE_BYTES)
#define SMEM_MAIN  (5 * KTILE_BYTES)                        // 80 KiB

#define PSTR 72   // prep_vt LDS row stride

typedef __attribute__((ext_vector_type(8)))  short bf16x8;
typedef __attribute__((ext_vector_type(4)))  float f32x4;
typedef __attribute__((ext_vector_type(16))) float f32x16;

#if __has_builtin(__builtin_amdgcn_exp2f)
#define EXP2F __builtin_amdgcn_exp2f
#else
#define EXP2F exp2f
#endif

#define MFMA32(a, b, c) __builtin_amdgcn_mfma_f32_32x32x16_bf16((a), (b), (c), 0, 0, 0)
#define WAITV(N) asm volatile("s_waitcnt vmcnt(" #N ")" ::: "memory")

__device__ inline unsigned short f2bf(float f) {
    union { float f; unsigned u; } x; x.f = f;
    unsigned r = (x.u + 0x7fffu + ((x.u >> 16) & 1u)) >> 16;  // RNE
    return (unsigned short)r;
}

__device__ inline unsigned cvt_pk_bf16(float lo, float hi) {
    unsigned r;
    asm("v_cvt_pk_bf16_f32 %0, %1, %2" : "=v"(r) : "v"(lo), "v"(hi));
    return r;
}

__device__ inline float fmax4(float a, float b, float c, float d) {
    return fmaxf(fmaxf(a, b), fmaxf(c, d));
}

// Build P^T B-fragment (K=16 slice) from 8 softmax'd f32 regs (R4-verified).
__device__ inline bf16x8 make_pfrag(float v0, float v1, float v2, float v3,
                                    float v4, float v5, float v6, float v7) {
    unsigned a0 = cvt_pk_bf16(v0, v1);
    unsigned a1 = cvt_pk_bf16(v2, v3);
    unsigned b0 = cvt_pk_bf16(v4, v5);
    unsigned b1 = cvt_pk_bf16(v6, v7);
    asm("v_permlane32_swap_b32 %0, %1" : "+v"(a0), "+v"(b0));
    asm("v_permlane32_swap_b32 %0, %1" : "+v"(a1), "+v"(b1));
    union { unsigned u[4]; bf16x8 v8; } u;
    u.u[0] = a0; u.u[1] = a1; u.u[2] = b0; u.u[3] = b1;
    return u.v8;
}

__device__ inline void gld16(const char* g, const char* l) {
    __builtin_amdgcn_global_load_lds(
        (const __attribute__((address_space(1))) unsigned int*)g,
        (__attribute__((address_space(3))) unsigned int*)l,
        16, 0, 0);
}

// ---------------- pre-pass A: K fp32 -> bf16*SCALE2, granule-transposed tiles
__global__ __launch_bounds__(256, 2)
void prep_k_kernel(const float* __restrict__ K, char* __restrict__ ws)
{
    __shared__ unsigned short kt[KVBLK * 136];
    const int tid  = threadIdx.x;
    const int kvt  = blockIdx.x;
    const int head = blockIdx.y;
    const float* Kh = K + ((size_t)head * LK_N + (size_t)kvt * KVBLK) * DD;
    #pragma unroll
    for (int i = 0; i < 4; ++i) {
        int c = tid + 256 * i;
        int r  = c >> 4;
        int c8 = c & 15;
        const float* src = Kh + (size_t)r * DD + c8 * 8;
        float4 a = *(const float4*)src;
        float4 b = *(const float4*)(src + 4);
        bf16x8 t;
        t[0] = (short)f2bf(a.x * SCALE2); t[1] = (short)f2bf(a.y * SCALE2);
        t[2] = (short)f2bf(a.z * SCALE2); t[3] = (short)f2bf(a.w * SCALE2);
        t[4] = (short)f2bf(b.x * SCALE2); t[5] = (short)f2bf(b.y * SCALE2);
        t[6] = (short)f2bf(b.z * SCALE2); t[7] = (short)f2bf(b.w * SCALE2);
        *(bf16x8*)&kt[r * 136 + c8 * 8] = t;
    }
    __syncthreads();
    char* dst = ws + ((size_t)head * NKV + kvt) * KTILE_BYTES;
    #pragma unroll
    for (int i = 0; i < 4; ++i) {
        int c = tid + 256 * i;
        int g = c >> 6;
        int r = c & 63;
        bf16x8 t = *(const bf16x8*)&kt[r * 136 + g * 8];
        *(bf16x8*)(dst + c * 16) = t;
    }
}

// ---------------- pre-pass B: V fp32 -> V^T bf16, granule-transposed tiles
__global__ __launch_bounds__(256, 2)
void prep_vt_kernel(const float* __restrict__ V, char* __restrict__ ws)
{
    __shared__ unsigned short vt[DD * PSTR];
    const int tid  = threadIdx.x;
    const int kvt  = blockIdx.x;
    const int head = blockIdx.y;
    const float* Vh = V + ((size_t)head * LK_N + (size_t)kvt * KVBLK) * DD;
    #pragma unroll
    for (int i = 0; i < 8; ++i) {
        int f = tid + 256 * i;
        int r  = f >> 5;
        int c4 = f & 31;
        float4 x = *(const float4*)(Vh + (size_t)r * DD + c4 * 4);
        vt[(c4 * 4 + 0) * PSTR + r] = f2bf(x.x);
        vt[(c4 * 4 + 1) * PSTR + r] = f2bf(x.y);
        vt[(c4 * 4 + 2) * PSTR + r] = f2bf(x.z);
        vt[(c4 * 4 + 3) * PSTR + r] = f2bf(x.w);
    }
    __syncthreads();
    char* dst = ws + WS_K_BYTES + ((size_t)head * NKV + kvt) * KTILE_BYTES;
    #pragma unroll
    for (int i = 0; i < 4; ++i) {
        int c = tid + 256 * i;
        int g = c >> 7;
        int d = c & 127;
        bf16x8 t = *(const bf16x8*)&vt[d * PSTR + g * 8];
        *(bf16x8*)(dst + c * 16) = t;
    }
}

// load the 4 V fragments of kv-slice KS into named regs from LDS base VB
#define LOADVF(a0, a1, a2, a3, VB, KS) { \
    a0 = *(const bf16x8*)((VB) + (((2 * (KS) + h) * 128 +  0 + l31) << 4)); \
    a1 = *(const bf16x8*)((VB) + (((2 * (KS) + h) * 128 + 32 + l31) << 4)); \
    a2 = *(const bf16x8*)((VB) + (((2 * (KS) + h) * 128 + 64 + l31) << 4)); \
    a3 = *(const bf16x8*)((VB) + (((2 * (KS) + h) * 128 + 96 + l31) << 4)); }

// one SM->PV round: 8 exp2 + pfrag + 5 MFMA (4 o_acc + 1 l-sum via ones-A)
#define PV_ROUND(S, B, r0, r1, r2, r3) { \
    float e0 = EXP2F(S[B + 0] - m_run), e1 = EXP2F(S[B + 1] - m_run); \
    float e2 = EXP2F(S[B + 2] - m_run), e3 = EXP2F(S[B + 3] - m_run); \
    float e4 = EXP2F(S[B + 4] - m_run), e5 = EXP2F(S[B + 5] - m_run); \
    float e6 = EXP2F(S[B + 6] - m_run), e7 = EXP2F(S[B + 7] - m_run); \
    bf16x8 pf = make_pfrag(e0, e1, e2, e3, e4, e5, e6, e7); \
    __builtin_amdgcn_s_setprio(1); \
    o_l      = MFMA32(ones8, pf, o_l); \
    o_acc[0] = MFMA32(r0, pf, o_acc[0]); \
    o_acc[1] = MFMA32(r1, pf, o_acc[1]); \
    o_acc[2] = MFMA32(r2, pf, o_acc[2]); \
    o_acc[3] = MFMA32(r3, pf, o_acc[3]); \
    __builtin_amdgcn_s_setprio(0); }

// ---------------- main kernel: 128q/4-wave, K ring x3 + V ring x2 (80 KB)
// -> TWO independent barrier domains per CU at iso per-tile overhead.
// Per tile: WAITV(4) (drains own K(t)+V(t); K(t+1) stays in flight) ->
// barrier -> issue V(t+1), K(t+2) -> process(t).
__global__ __launch_bounds__(256, 2)
void attn_main_kernel(const float* __restrict__ Q, const char* __restrict__ kws,
                      const char* __restrict__ vws, float* __restrict__ O)
{
    extern __shared__ char smem[];   // [K x3 | V x2], 16 KiB slots

    const int tid  = threadIdx.x;
    const int lane = tid & 63;
    const int wave = tid >> 6;      // 0..3
    const int l31  = lane & 31;
    const int h    = lane >> 5;     // half: 0/1

    // XCD swizzle: 512 blocks, 8 XCDs, 64-block chunks (bijective)
    const int bid  = blockIdx.x;
    const int sid  = (bid & 7) * (NQB * NHEADS / 8) + (bid >> 3);
    const int head = sid >> 4;      // /NQB
    const int qb   = sid & 15;      // %NQB

    const float* Qh = Q + (size_t)head * LQ_N * DD;
    float*       Oh = O + (size_t)head * LQ_N * DD;
    const char*  kt_g = kws + (size_t)head * NKV * KTILE_BYTES;
    const char*  vt_g = vws + (size_t)head * NKV * KTILE_BYTES;

    // ---- Q^T B-fragments: lane holds Q[q = qrow][d = 16*kd + 8*h + j]
    const int qrow = qb * QBLK + wave * 32 + l31;
    bf16x8 qf[8];
    {
        const float* qp = Qh + (size_t)qrow * DD + 8 * h;
        #pragma unroll
        for (int kd = 0; kd < 8; ++kd) {
            float4 a = *(const float4*)(qp + 16 * kd);
            float4 b = *(const float4*)(qp + 16 * kd + 4);
            bf16x8 t;
            t[0] = (short)f2bf(a.x); t[1] = (short)f2bf(a.y);
            t[2] = (short)f2bf(a.z); t[3] = (short)f2bf(a.w);
            t[4] = (short)f2bf(b.x); t[5] = (short)f2bf(b.y);
            t[6] = (short)f2bf(b.z); t[7] = (short)f2bf(b.w);
            qf[kd] = t;
        }
    }
    asm volatile("s_waitcnt vmcnt(0)" ::: "memory");  // clean vmcnt base

    bf16x8 ones8;
    #pragma unroll
    for (int i = 0; i < 8; ++i) ones8[i] = (short)0x3F80;   // bf16 1.0

    f32x16 o_acc[4], o_l;
    #pragma unroll
    for (int nt = 0; nt < 4; ++nt)
        #pragma unroll
        for (int i = 0; i < 16; ++i) o_acc[nt][i] = 0.f;
    #pragma unroll
    for (int i = 0; i < 16; ++i) o_l[i] = 0.f;
    float m_run = -1e30f;

    // stage K tile t -> slot t%3 ; V tile t -> slot t&1 (4 gld16 each)
    auto issue_k = [&](int t) {
        const char* ks = kt_g + (size_t)t * KTILE_BYTES;
        const char* kl = smem + KB_OFF(t % 3);
        #pragma unroll
        for (int i = 0; i < 4; ++i) {
            int off = (tid + 256 * i) * 16;
            gld16(ks + off, kl + off);
        }
    };
    auto issue_v = [&](int t) {
        const char* vs = vt_g + (size_t)t * KTILE_BYTES;
        const char* vl = smem + VB_OFF(t & 1);
        #pragma unroll
        for (int i = 0; i < 4; ++i) {
            int off = (tid + 256 * i) * 16;
            gld16(vs + off, vl + off);
        }
    };

    // process one kv tile entirely from LDS (no vmem ops inside)
    auto process = [&](int t) {
        const char* kb    = smem + KB_OFF(t % 3);
        const char* vbase = smem + VB_OFF(t & 1);

        // ---- S^T = K Q^T (16 ds_read_b128 + 16 MFMA)
        f32x16 s0, s1;
        #pragma unroll
        for (int i = 0; i < 16; ++i) { s0[i] = 0.f; s1[i] = 0.f; }
        __builtin_amdgcn_s_setprio(1);
        #pragma unroll
        for (int kd = 0; kd < 8; ++kd) {
            bf16x8 kf0 = *(const bf16x8*)(kb + (((2 * kd + h) * 64 + l31) << 4));
            bf16x8 kf1 = *(const bf16x8*)(kb + (((2 * kd + h) * 64 + 32 + l31) << 4));
            s0 = MFMA32(kf0, qf[kd], s0);
            s1 = MFMA32(kf1, qf[kd], s1);
        }
        __builtin_amdgcn_s_setprio(0);

        // ---- batch V prefetch for rounds 0,1 (LDS pipe works under softmax)
        bf16x8 va0, va1, va2, va3, vb0, vb1, vb2, vb3;
        LOADVF(va0, va1, va2, va3, vbase, 0);
        LOADVF(vb0, vb1, vb2, vb3, vbase, 1);

        // ---- online softmax (log2 domain), q = l31 lane-local
        float x0 = fmax4(s0[0],  s0[1],  s0[2],  s0[3]);
        float x1 = fmax4(s0[4],  s0[5],  s0[6],  s0[7]);
        float x2 = fmax4(s0[8],  s0[9],  s0[10], s0[11]);
        float x3 = fmax4(s0[12], s0[13], s0[14], s0[15]);
        float y0 = fmax4(s1[0],  s1[1],  s1[2],  s1[3]);
        float y1 = fmax4(s1[4],  s1[5],  s1[6],  s1[7]);
        float y2 = fmax4(s1[8],  s1[9],  s1[10], s1[11]);
        float y3 = fmax4(s1[12], s1[13], s1[14], s1[15]);
        float pm = fmaxf(fmaxf(fmaxf(x0, x1), fmaxf(x2, x3)),
                         fmaxf(fmaxf(y0, y1), fmaxf(y2, y3)));
        pm = fmaxf(pm, __shfl_xor(pm, 32));

        if (!__all(pm <= m_run + 8.0f)) {     // defer-max (T13)
            float mn = fmaxf(m_run, pm);
            float al = EXP2F(m_run - mn);
            m_run = mn;
            #pragma unroll
            for (int nt = 0; nt < 4; ++nt)
                #pragma unroll
                for (int i = 0; i < 16; ++i) o_acc[nt][i] *= al;
            #pragma unroll
            for (int i = 0; i < 16; ++i) o_l[i] *= al;
        }

        // ---- 4 SM->PV rounds; reload each reg set one round ahead
        PV_ROUND(s0, 0, va0, va1, va2, va3);    // KS0
        LOADVF(va0, va1, va2, va3, vbase, 2);   // prefetch KS2
        PV_ROUND(s0, 8, vb0, vb1, vb2, vb3);    // KS1
        LOADVF(vb0, vb1, vb2, vb3, vbase, 3);   // prefetch KS3
        PV_ROUND(s1, 0, va0, va1, va2, va3);    // KS2
        PV_ROUND(s1, 8, vb0, vb1, vb2, vb3);    // KS3
    };

    // ---- prologue: K(0), V(0), K(1) — queue order matters for WAITV(4)
    issue_k(0);
    issue_v(0);
    issue_k(1);

    // ---- per tile: drain own K(t)+V(t) (K(t+1) stays in flight), barrier
    // (all waves' shares landed), then issue V(t+1)->slot(t-1), K(t+2)->
    // slot(t-1): both consumed before barrier(t) -> WAR-safe.
    for (int t = 0; t < NKV; ++t) {
        if (t < NKV - 1) WAITV(4);
        else             WAITV(0);
        __builtin_amdgcn_s_barrier();
        __builtin_amdgcn_sched_barrier(0);   // keep issues below the barrier
        if (t + 1 < NKV) issue_v(t + 1);
        if (t + 2 < NKV) issue_k(t + 2);
        process(t);
    }

    // ---- epilogue: O[q][d] = O^T / l ; l = o_l[0] (all elements identical)
    float inv = 1.0f / o_l[0];
    float* op = Oh + (size_t)qrow * DD;
    #pragma unroll
    for (int nt = 0; nt < 4; ++nt)
        #pragma unroll
        for (int p = 0; p < 4; ++p) {
            int dbase = 32 * nt + 8 * p + 4 * h;
            float4 w;
            w.x = o_acc[nt][4 * p + 0] * inv;
            w.y = o_acc[nt][4 * p + 1] * inv;
            w.z = o_acc[nt][4 * p + 2] * inv;
            w.w = o_acc[nt][4 * p + 3] * inv;
            *(float4*)(op + dbase) = w;
        }
}

// ================= fallback (round-1 kernel, used if ws too small) ==========
#define KSTRIDE  136
#define VTSTRIDE 40
#define FKV 32

__global__ __launch_bounds__(256, 2)
void attn_fwd_fallback(const float* __restrict__ Q, const float* __restrict__ K,
                       const float* __restrict__ V, float* __restrict__ O)
{
    __shared__ unsigned short k_lds[FKV * KSTRIDE];
    __shared__ unsigned short vt_lds[DD * VTSTRIDE];
    __shared__ unsigned short p_lds2[4 * 16 * VTSTRIDE];

    const int tid  = threadIdx.x;
    const int lane = tid & 63;
    const int wave = tid >> 6;
    const int head = blockIdx.y;
    const int qb   = blockIdx.x;

    const float* Qh = Q + (size_t)head * LQ_N * DD;
    const float* Kh = K + (size_t)head * LK_N * DD;
    const float* Vh = V + (size_t)head * LK_N * DD;
    float*       Oh = O + (size_t)head * LQ_N * DD;

    const int r16 = lane & 15;
    const int g   = lane >> 4;

    const int qrow = qb * 64 + wave * 16 + r16;
    bf16x8 qf[4];
    {
        const float* qp = Qh + (size_t)qrow * DD + 8 * g;
        #pragma unroll
        for (int kt = 0; kt < 4; ++kt) {
            float4 a = *(const float4*)(qp + 32 * kt);
            float4 b = *(const float4*)(qp + 32 * kt + 4);
            bf16x8 t;
            t[0] = (short)f2bf(a.x * SCALE); t[1] = (short)f2bf(a.y * SCALE);
            t[2] = (short)f2bf(a.z * SCALE); t[3] = (short)f2bf(a.w * SCALE);
            t[4] = (short)f2bf(b.x * SCALE); t[5] = (short)f2bf(b.y * SCALE);
            t[6] = (short)f2bf(b.z * SCALE); t[7] = (short)f2bf(b.w * SCALE);
            qf[kt] = t;
        }
    }

    f32x4 o_acc[8];
    #pragma unroll
    for (int dt = 0; dt < 8; ++dt) o_acc[dt] = (f32x4){0.f, 0.f, 0.f, 0.f};
    float m_run[4], l_run[4];
    #pragma unroll
    for (int r = 0; r < 4; ++r) { m_run[r] = -1e30f; l_run[r] = 0.f; }

    for (int kv = 0; kv < LK_N / FKV; ++kv) {
        const float* Kt = Kh + (size_t)kv * FKV * DD;
        const float* Vt = Vh + (size_t)kv * FKV * DD;
        __syncthreads();
        #pragma unroll
        for (int i = 0; i < 4; ++i) {
            int f = tid + 256 * i;
            int row = f >> 5, colf = f & 31;
            float4 x = *(const float4*)(Kt + (size_t)row * DD + colf * 4);
            ushort4 pk;
            pk.x = f2bf(x.x); pk.y = f2bf(x.y); pk.z = f2bf(x.z); pk.w = f2bf(x.w);
            *(ushort4*)(&k_lds[row * KSTRIDE + colf * 4]) = pk;
        }
        #pragma unroll
        for (int i = 0; i < 4; ++i) {
            int f = tid + 256 * i;
            int row = f >> 5, colf = f & 31;
            float4 x = *(const float4*)(Vt + (size_t)row * DD + colf * 4);
            vt_lds[(colf * 4 + 0) * VTSTRIDE + row] = f2bf(x.x);
            vt_lds[(colf * 4 + 1) * VTSTRIDE + row] = f2bf(x.y);
            vt_lds[(colf * 4 + 2) * VTSTRIDE + row] = f2bf(x.z);
            vt_lds[(colf * 4 + 3) * VTSTRIDE + row] = f2bf(x.w);
        }
        __syncthreads();

        f32x4 s0 = (f32x4){0.f,0.f,0.f,0.f};
        f32x4 s1 = (f32x4){0.f,0.f,0.f,0.f};
        #pragma unroll
        for (int kt = 0; kt < 4; ++kt) {
            bf16x8 kf0 = *(const bf16x8*)&k_lds[(r16)      * KSTRIDE + 32 * kt + 8 * g];
            bf16x8 kf1 = *(const bf16x8*)&k_lds[(16 + r16) * KSTRIDE + 32 * kt + 8 * g];
            s0 = __builtin_amdgcn_mfma_f32_16x16x32_bf16(qf[kt], kf0, s0, 0, 0, 0);
            s1 = __builtin_amdgcn_mfma_f32_16x16x32_bf16(qf[kt], kf1, s1, 0, 0, 0);
        }

        float alpha[4];
        f32x4 p0, p1;
        #pragma unroll
        for (int r = 0; r < 4; ++r) {
            float t = fmaxf(s0[r], s1[r]);
            t = fmaxf(t, __shfl_xor(t, 1));
            t = fmaxf(t, __shfl_xor(t, 2));
            t = fmaxf(t, __shfl_xor(t, 4));
            t = fmaxf(t, __shfl_xor(t, 8));
            float mn = fmaxf(m_run[r], t);
            alpha[r] = __expf(m_run[r] - mn);
            m_run[r] = mn;
            p0[r] = __expf(s0[r] - mn);
            p1[r] = __expf(s1[r] - mn);
            float su = p0[r] + p1[r];
            su += __shfl_xor(su, 1);
            su += __shfl_xor(su, 2);
            su += __shfl_xor(su, 4);
            su += __shfl_xor(su, 8);
            l_run[r] = l_run[r] * alpha[r] + su;
        }

        unsigned short* pw = &p_lds2[wave * 16 * VTSTRIDE];
        #pragma unroll
        for (int r = 0; r < 4; ++r) {
            int row = 4 * g + r;
            pw[row * VTSTRIDE + r16]      = f2bf(p0[r]);
            pw[row * VTSTRIDE + 16 + r16] = f2bf(p1[r]);
        }
        bf16x8 pf = *(const bf16x8*)&pw[r16 * VTSTRIDE + 8 * g];

        #pragma unroll
        for (int dt = 0; dt < 8; ++dt) {
            #pragma unroll
            for (int r = 0; r < 4; ++r) o_acc[dt][r] *= alpha[r];
        }
        #pragma unroll
        for (int dt = 0; dt < 8; ++dt) {
            bf16x8 vf = *(const bf16x8*)&vt_lds[(16 * dt + r16) * VTSTRIDE + 8 * g];
            o_acc[dt] = __builtin_amdgcn_mfma_f32_16x16x32_bf16(pf, vf, o_acc[dt], 0, 0, 0);
        }
    }

    #pragma unroll
    for (int r = 0; r < 4; ++r) {
        float inv = 1.0f / l_run[r];
        int row = qb * 64 + wave * 16 + 4 * g + r;
        float* op = Oh + (size_t)row * DD + r16;
        #pragma unroll
        for (int dt = 0; dt < 8; ++dt)
            op[16 * dt] = o_acc[dt][r] * inv;
    }
}

extern "C" void kernel_launch(void* const* d_in, const int* in_sizes, int n_in,
                              void* d_out, int out_size, void* d_ws, size_t ws_size,
                              hipStream_t stream) {
    const float* q = (const float*)d_in[0];
    const float* k = (const float*)d_in[1];
    const float* v = (const float*)d_in[2];
    float* o = (float*)d_out;

    hipError_t attr_ok = hipFuncSetAttribute(
        (const void*)attn_main_kernel,
        hipFuncAttributeMaxDynamicSharedMemorySize, SMEM_MAIN);

    if (ws_size >= WS_NEED && attr_ok == hipSuccess) {
        char* ws = (char*)d_ws;
        prep_k_kernel <<<dim3(NKV, NHEADS), 256, 0, stream>>>(k, ws);
        prep_vt_kernel<<<dim3(NKV, NHEADS), 256, 0, stream>>>(v, ws);
        attn_main_kernel<<<dim3(NQB * NHEADS), 256, SMEM_MAIN, stream>>>(
            q, ws, ws + WS_K_BYTES, o);
    } else {
        attn_fwd_fallback<<<dim3(LQ_N / 64, NHEADS), 256, 0, stream>>>(q, k, v, o);
    }
}

// Round 19
// 95.488 us; speedup vs baseline: 1.0729x; 1.0729x over previous
//
#include <hip/hip_runtime.h>
#include <hip/hip_bf16.h>
#include <cstdint>

// Problem constants (B=2, H=16 -> 32 heads)
#define LQ_N   2048
#define LK_N   2048
#define DD     128
#define NHEADS 32
#define QBLK   256               // q rows per block (8 waves x 32 rows)
#define KVBLK  64
#define NKV    (LK_N / KVBLK)    // 32 kv tiles
#define NQB    (LQ_N / QBLK)     // 8 q blocks
#define SCALE  0.08838834764831845f            // 1/sqrt(128)
#define SCALE2 0.1275525003267101f             // SCALE * log2(e)

// ws layout: [K tiles][V^T tiles], granule-transposed (R5-verified, conflict-free)
#define KTILE_BYTES (KVBLK * DD * 2)                        // 16 KiB per tile
#define WS_K_BYTES  ((size_t)NHEADS * NKV * KTILE_BYTES)    // 16 MiB
#define WS_NEED     (2 * WS_K_BYTES)                        // 32 MiB

// main-kernel dynamic LDS: K ring x4 + V ring x4 = 128 KiB -> 1 block/CU
#define RING       4
#define SMEM_MAIN  (2 * RING * KTILE_BYTES)

#define PSTR 72   // prep V-transpose LDS row stride

typedef __attribute__((ext_vector_type(8)))  short bf16x8;
typedef __attribute__((ext_vector_type(4)))  float f32x4;
typedef __attribute__((ext_vector_type(16))) float f32x16;

#if __has_builtin(__builtin_amdgcn_exp2f)
#define EXP2F __builtin_amdgcn_exp2f
#else
#define EXP2F exp2f
#endif

#define MFMA32(a, b, c) __builtin_amdgcn_mfma_f32_32x32x16_bf16((a), (b), (c), 0, 0, 0)
#define WAITV(N) asm volatile("s_waitcnt vmcnt(" #N ")" ::: "memory")

__device__ inline unsigned short f2bf(float f) {
    union { float f; unsigned u; } x; x.f = f;
    unsigned r = (x.u + 0x7fffu + ((x.u >> 16) & 1u)) >> 16;  // RNE
    return (unsigned short)r;
}

__device__ inline unsigned cvt_pk_bf16(float lo, float hi) {
    unsigned r;
    asm("v_cvt_pk_bf16_f32 %0, %1, %2" : "=v"(r) : "v"(lo), "v"(hi));
    return r;
}

__device__ inline float fmax4(float a, float b, float c, float d) {
    return fmaxf(fmaxf(a, b), fmaxf(c, d));
}

// Build P^T B-fragment (K=16 slice) from 8 softmax'd f32 regs (R4-verified).
__device__ inline bf16x8 make_pfrag(float v0, float v1, float v2, float v3,
                                    float v4, float v5, float v6, float v7) {
    unsigned a0 = cvt_pk_bf16(v0, v1);
    unsigned a1 = cvt_pk_bf16(v2, v3);
    unsigned b0 = cvt_pk_bf16(v4, v5);
    unsigned b1 = cvt_pk_bf16(v6, v7);
    asm("v_permlane32_swap_b32 %0, %1" : "+v"(a0), "+v"(b0));
    asm("v_permlane32_swap_b32 %0, %1" : "+v"(a1), "+v"(b1));
    union { unsigned u[4]; bf16x8 v8; } u;
    u.u[0] = a0; u.u[1] = a1; u.u[2] = b0; u.u[3] = b1;
    return u.v8;
}

__device__ inline void gld16(const char* g, const char* l) {
    __builtin_amdgcn_global_load_lds(
        (const __attribute__((address_space(1))) unsigned int*)g,
        (__attribute__((address_space(3))) unsigned int*)l,
        16, 0, 0);
}

// ---------------- merged pre-pass: K->bf16*SCALE2 and V->V^T bf16, both
// granule-transposed tile-major (phases share one LDS buffer)
__global__ __launch_bounds__(256, 2)
void prep_kv_kernel(const float* __restrict__ K, const float* __restrict__ V,
                    char* __restrict__ ws)
{
    __shared__ unsigned short buf[DD * PSTR];   // 18.4 KB, reused K then V
    const int tid  = threadIdx.x;
    const int kvt  = blockIdx.x;
    const int head = blockIdx.y;

    // ---- phase 1: K tile -> bf16 (scaled), granule-transposed
    {
        unsigned short* kt = buf;   // use as [64][136]
        const float* Kh = K + ((size_t)head * LK_N + (size_t)kvt * KVBLK) * DD;
        #pragma unroll
        for (int i = 0; i < 4; ++i) {
            int c = tid + 256 * i;          // 16B chunk id, 1024 per tile
            int r  = c >> 4;                // kv row 0..63
            int c8 = c & 15;                // 8-elem group along D
            const float* src = Kh + (size_t)r * DD + c8 * 8;
            float4 a = *(const float4*)src;
            float4 b = *(const float4*)(src + 4);
            bf16x8 t;
            t[0] = (short)f2bf(a.x * SCALE2); t[1] = (short)f2bf(a.y * SCALE2);
            t[2] = (short)f2bf(a.z * SCALE2); t[3] = (short)f2bf(a.w * SCALE2);
            t[4] = (short)f2bf(b.x * SCALE2); t[5] = (short)f2bf(b.y * SCALE2);
            t[6] = (short)f2bf(b.z * SCALE2); t[7] = (short)f2bf(b.w * SCALE2);
            *(bf16x8*)&kt[r * 136 + c8 * 8] = t;
        }
        __syncthreads();
        char* dst = ws + ((size_t)head * NKV + kvt) * KTILE_BYTES;
        #pragma unroll
        for (int i = 0; i < 4; ++i) {
            int c = tid + 256 * i;
            int g = c >> 6;                 // granule col 0..15
            int r = c & 63;                 // row
            bf16x8 t = *(const bf16x8*)&kt[r * 136 + g * 8];
            *(bf16x8*)(dst + c * 16) = t;
        }
    }
    __syncthreads();   // K phase done with buf before V phase overwrites

    // ---- phase 2: V tile -> V^T bf16, granule-transposed
    {
        unsigned short* vt = buf;   // use as [128][72]
        const float* Vh = V + ((size_t)head * LK_N + (size_t)kvt * KVBLK) * DD;
        #pragma unroll
        for (int i = 0; i < 8; ++i) {
            int f = tid + 256 * i;          // float4 id, 2048 per tile
            int r  = f >> 5;                // kv row 0..63
            int c4 = f & 31;                // float4 along D
            float4 x = *(const float4*)(Vh + (size_t)r * DD + c4 * 4);
            vt[(c4 * 4 + 0) * PSTR + r] = f2bf(x.x);
            vt[(c4 * 4 + 1) * PSTR + r] = f2bf(x.y);
            vt[(c4 * 4 + 2) * PSTR + r] = f2bf(x.z);
            vt[(c4 * 4 + 3) * PSTR + r] = f2bf(x.w);
        }
        __syncthreads();
        char* dst = ws + WS_K_BYTES + ((size_t)head * NKV + kvt) * KTILE_BYTES;
        #pragma unroll
        for (int i = 0; i < 4; ++i) {
            int c = tid + 256 * i;
            int g = c >> 7;                 // granule col 0..7 (kv)
            int d = c & 127;                // row (d)
            bf16x8 t = *(const bf16x8*)&vt[d * PSTR + g * 8];
            *(bf16x8*)(dst + c * 16) = t;
        }
    }
}

// load the 4 V fragments of kv-slice KS into named regs from LDS base VB
#define LOADVF(a0, a1, a2, a3, VB, KS) { \
    a0 = *(const bf16x8*)((VB) + (((2 * (KS) + h) * 128 +  0 + l31) << 4)); \
    a1 = *(const bf16x8*)((VB) + (((2 * (KS) + h) * 128 + 32 + l31) << 4)); \
    a2 = *(const bf16x8*)((VB) + (((2 * (KS) + h) * 128 + 64 + l31) << 4)); \
    a3 = *(const bf16x8*)((VB) + (((2 * (KS) + h) * 128 + 96 + l31) << 4)); }

// one SM->PV round: 8 exp2 + pfrag + 5 MFMA (4 o_acc + 1 l-sum via ones-A)
#define PV_ROUND(S, B, r0, r1, r2, r3) { \
    float e0 = EXP2F(S[B + 0] - m_run), e1 = EXP2F(S[B + 1] - m_run); \
    float e2 = EXP2F(S[B + 2] - m_run), e3 = EXP2F(S[B + 3] - m_run); \
    float e4 = EXP2F(S[B + 4] - m_run), e5 = EXP2F(S[B + 5] - m_run); \
    float e6 = EXP2F(S[B + 6] - m_run), e7 = EXP2F(S[B + 7] - m_run); \
    bf16x8 pf = make_pfrag(e0, e1, e2, e3, e4, e5, e6, e7); \
    __builtin_amdgcn_s_setprio(1); \
    o_l      = MFMA32(ones8, pf, o_l); \
    o_acc[0] = MFMA32(r0, pf, o_acc[0]); \
    o_acc[1] = MFMA32(r1, pf, o_acc[1]); \
    o_acc[2] = MFMA32(r2, pf, o_acc[2]); \
    o_acc[3] = MFMA32(r3, pf, o_acc[3]); \
    __builtin_amdgcn_s_setprio(0); }

// ---------------- main kernel: 256q/8-wave, 4-deep K+V LDS rings,
// per tile: drain-own-share -> barrier -> issue(t+2) -> process(t)
// (R15/R17 measured best: 91.5 us, MfmaUtil 36%)
__global__ __launch_bounds__(512, 1)
void attn_main_kernel(const float* __restrict__ Q, const char* __restrict__ kws,
                      const char* __restrict__ vws, float* __restrict__ O)
{
    extern __shared__ char smem[];   // [K ring x4 | V ring x4], 16 KiB slots

    const int tid  = threadIdx.x;
    const int lane = tid & 63;
    const int wave = tid >> 6;      // 0..7
    const int l31  = lane & 31;
    const int h    = lane >> 5;     // half: 0/1

    // XCD swizzle: 256 blocks, 8 XCDs, 32-block chunks -> 4 heads per XCD L2
    const int bid  = blockIdx.x;
    const int sid  = (bid & 7) * (NQB * NHEADS / 8) + (bid >> 3);
    const int head = sid >> 3;      // /NQB
    const int qb   = sid & 7;       // %NQB

    const float* Qh = Q + (size_t)head * LQ_N * DD;
    float*       Oh = O + (size_t)head * LQ_N * DD;
    const char*  kt_g = kws + (size_t)head * NKV * KTILE_BYTES;
    const char*  vt_g = vws + (size_t)head * NKV * KTILE_BYTES;

    // ---- Q^T B-fragments: lane holds Q[q = qrow][d = 16*kd + 8*h + j]
    const int qrow = qb * QBLK + wave * 32 + l31;
    bf16x8 qf[8];
    {
        const float* qp = Qh + (size_t)qrow * DD + 8 * h;
        #pragma unroll
        for (int kd = 0; kd < 8; ++kd) {
            float4 a = *(const float4*)(qp + 16 * kd);
            float4 b = *(const float4*)(qp + 16 * kd + 4);
            bf16x8 t;
            t[0] = (short)f2bf(a.x); t[1] = (short)f2bf(a.y);
            t[2] = (short)f2bf(a.z); t[3] = (short)f2bf(a.w);
            t[4] = (short)f2bf(b.x); t[5] = (short)f2bf(b.y);
            t[6] = (short)f2bf(b.z); t[7] = (short)f2bf(b.w);
            qf[kd] = t;
        }
    }
    asm volatile("s_waitcnt vmcnt(0)" ::: "memory");  // clean vmcnt base

    bf16x8 ones8;
    #pragma unroll
    for (int i = 0; i < 8; ++i) ones8[i] = (short)0x3F80;   // bf16 1.0

    f32x16 o_acc[4], o_l;
    #pragma unroll
    for (int nt = 0; nt < 4; ++nt)
        #pragma unroll
        for (int i = 0; i < 16; ++i) o_acc[nt][i] = 0.f;
    #pragma unroll
    for (int i = 0; i < 16; ++i) o_l[i] = 0.f;
    float m_run = -1e30f;

    // stage tile t: K -> slot t%4, V -> slot 4 + t%4 (4 gld16/thread/tile)
    auto issue_t = [&](int t) {
        const char* ks = kt_g + (size_t)t * KTILE_BYTES;
        const char* vs = vt_g + (size_t)t * KTILE_BYTES;
        const char* kl = smem + (size_t)(t & 3) * KTILE_BYTES;
        const char* vl = smem + (size_t)(RING + (t & 3)) * KTILE_BYTES;
        #pragma unroll
        for (int i = 0; i < 2; ++i) {
            int off = (tid + 512 * i) * 16;
            gld16(ks + off, kl + off);
            gld16(vs + off, vl + off);
        }
    };

    // process one kv tile entirely from LDS (no vmem ops inside)
    auto process = [&](int t) {
        const char* kb = smem + (size_t)(t & 3) * KTILE_BYTES;
        const char* vbase = smem + (size_t)(RING + (t & 3)) * KTILE_BYTES;

        // ---- S^T = K Q^T (16 ds_read_b128 + 16 MFMA)
        f32x16 s0, s1;
        #pragma unroll
        for (int i = 0; i < 16; ++i) { s0[i] = 0.f; s1[i] = 0.f; }
        __builtin_amdgcn_s_setprio(1);
        #pragma unroll
        for (int kd = 0; kd < 8; ++kd) {
            bf16x8 kf0 = *(const bf16x8*)(kb + (((2 * kd + h) * 64 + l31) << 4));
            bf16x8 kf1 = *(const bf16x8*)(kb + (((2 * kd + h) * 64 + 32 + l31) << 4));
            s0 = MFMA32(kf0, qf[kd], s0);
            s1 = MFMA32(kf1, qf[kd], s1);
        }
        __builtin_amdgcn_s_setprio(0);

        // ---- batch V prefetch for rounds 0,1 (LDS pipe works under softmax)
        bf16x8 va0, va1, va2, va3, vb0, vb1, vb2, vb3;
        LOADVF(va0, va1, va2, va3, vbase, 0);
        LOADVF(vb0, vb1, vb2, vb3, vbase, 1);

        // ---- online softmax (log2 domain), q = l31 lane-local
        float x0 = fmax4(s0[0],  s0[1],  s0[2],  s0[3]);
        float x1 = fmax4(s0[4],  s0[5],  s0[6],  s0[7]);
        float x2 = fmax4(s0[8],  s0[9],  s0[10], s0[11]);
        float x3 = fmax4(s0[12], s0[13], s0[14], s0[15]);
        float y0 = fmax4(s1[0],  s1[1],  s1[2],  s1[3]);
        float y1 = fmax4(s1[4],  s1[5],  s1[6],  s1[7]);
        float y2 = fmax4(s1[8],  s1[9],  s1[10], s1[11]);
        float y3 = fmax4(s1[12], s1[13], s1[14], s1[15]);
        float pm = fmaxf(fmaxf(fmaxf(x0, x1), fmaxf(x2, x3)),
                         fmaxf(fmaxf(y0, y1), fmaxf(y2, y3)));
        pm = fmaxf(pm, __shfl_xor(pm, 32));

        if (!__all(pm <= m_run + 8.0f)) {     // defer-max (T13)
            float mn = fmaxf(m_run, pm);
            float al = EXP2F(m_run - mn);
            m_run = mn;
            #pragma unroll
            for (int nt = 0; nt < 4; ++nt)
                #pragma unroll
                for (int i = 0; i < 16; ++i) o_acc[nt][i] *= al;
            #pragma unroll
            for (int i = 0; i < 16; ++i) o_l[i] *= al;
        }

        // ---- 4 SM->PV rounds; reload each reg set one round ahead
        PV_ROUND(s0, 0, va0, va1, va2, va3);    // KS0
        LOADVF(va0, va1, va2, va3, vbase, 2);   // prefetch KS2
        PV_ROUND(s0, 8, vb0, vb1, vb2, vb3);    // KS1
        LOADVF(vb0, vb1, vb2, vb3, vbase, 3);   // prefetch KS3
        PV_ROUND(s1, 0, va0, va1, va2, va3);    // KS2
        PV_ROUND(s1, 8, vb0, vb1, vb2, vb3);    // KS3
    };

    // ---- prologue: stage tiles 0,1 (8 loads/thread in flight)
    issue_t(0);
    issue_t(1);

    // ---- per tile: drain OWN share of tile t BEFORE the barrier (vmcnt is
    // per-wave; barrier then proves ALL waves' shares landed — R13 bug fix),
    // then issue tile t+2 into slot(t-2) (WAR-safe: readers done 2 barriers ago).
    for (int t = 0; t < NKV; ++t) {
        if (t < NKV - 1) WAITV(4);   // keep tile t+1's 4 loads in flight
        else             WAITV(0);   // last tile: nothing newer
        __builtin_amdgcn_s_barrier();
        __builtin_amdgcn_sched_barrier(0);   // keep issue below the barrier
        if (t + 2 < NKV) issue_t(t + 2);
        process(t);
    }

    // ---- epilogue: O[q][d] = O^T / l ; l = o_l[0] (all elements identical)
    float inv = 1.0f / o_l[0];
    float* op = Oh + (size_t)qrow * DD;
    #pragma unroll
    for (int nt = 0; nt < 4; ++nt)
        #pragma unroll
        for (int p = 0; p < 4; ++p) {
            int dbase = 32 * nt + 8 * p + 4 * h;
            float4 w;
            w.x = o_acc[nt][4 * p + 0] * inv;
            w.y = o_acc[nt][4 * p + 1] * inv;
            w.z = o_acc[nt][4 * p + 2] * inv;
            w.w = o_acc[nt][4 * p + 3] * inv;
            *(float4*)(op + dbase) = w;
        }
}

// ================= fallback (round-1 kernel, used if ws too small) ==========
#define KSTRIDE  136
#define VTSTRIDE 40
#define FKV 32

__global__ __launch_bounds__(256, 2)
void attn_fwd_fallback(const float* __restrict__ Q, const float* __restrict__ K,
                       const float* __restrict__ V, float* __restrict__ O)
{
    __shared__ unsigned short k_lds[FKV * KSTRIDE];
    __shared__ unsigned short vt_lds[DD * VTSTRIDE];
    __shared__ unsigned short p_lds2[4 * 16 * VTSTRIDE];

    const int tid  = threadIdx.x;
    const int lane = tid & 63;
    const int wave = tid >> 6;
    const int head = blockIdx.y;
    const int qb   = blockIdx.x;

    const float* Qh = Q + (size_t)head * LQ_N * DD;
    const float* Kh = K + (size_t)head * LK_N * DD;
    const float* Vh = V + (size_t)head * LK_N * DD;
    float*       Oh = O + (size_t)head * LQ_N * DD;

    const int r16 = lane & 15;
    const int g   = lane >> 4;

    const int qrow = qb * 64 + wave * 16 + r16;
    bf16x8 qf[4];
    {
        const float* qp = Qh + (size_t)qrow * DD + 8 * g;
        #pragma unroll
        for (int kt = 0; kt < 4; ++kt) {
            float4 a = *(const float4*)(qp + 32 * kt);
            float4 b = *(const float4*)(qp + 32 * kt + 4);
            bf16x8 t;
            t[0] = (short)f2bf(a.x * SCALE); t[1] = (short)f2bf(a.y * SCALE);
            t[2] = (short)f2bf(a.z * SCALE); t[3] = (short)f2bf(a.w * SCALE);
            t[4] = (short)f2bf(b.x * SCALE); t[5] = (short)f2bf(b.y * SCALE);
            t[6] = (short)f2bf(b.z * SCALE); t[7] = (short)f2bf(b.w * SCALE);
            qf[kt] = t;
        }
    }

    f32x4 o_acc[8];
    #pragma unroll
    for (int dt = 0; dt < 8; ++dt) o_acc[dt] = (f32x4){0.f, 0.f, 0.f, 0.f};
    float m_run[4], l_run[4];
    #pragma unroll
    for (int r = 0; r < 4; ++r) { m_run[r] = -1e30f; l_run[r] = 0.f; }

    for (int kv = 0; kv < LK_N / FKV; ++kv) {
        const float* Kt = Kh + (size_t)kv * FKV * DD;
        const float* Vt = Vh + (size_t)kv * FKV * DD;
        __syncthreads();
        #pragma unroll
        for (int i = 0; i < 4; ++i) {
            int f = tid + 256 * i;
            int row = f >> 5, colf = f & 31;
            float4 x = *(const float4*)(Kt + (size_t)row * DD + colf * 4);
            ushort4 pk;
            pk.x = f2bf(x.x); pk.y = f2bf(x.y); pk.z = f2bf(x.z); pk.w = f2bf(x.w);
            *(ushort4*)(&k_lds[row * KSTRIDE + colf * 4]) = pk;
        }
        #pragma unroll
        for (int i = 0; i < 4; ++i) {
            int f = tid + 256 * i;
            int row = f >> 5, colf = f & 31;
            float4 x = *(const float4*)(Vt + (size_t)row * DD + colf * 4);
            vt_lds[(colf * 4 + 0) * VTSTRIDE + row] = f2bf(x.x);
            vt_lds[(colf * 4 + 1) * VTSTRIDE + row] = f2bf(x.y);
            vt_lds[(colf * 4 + 2) * VTSTRIDE + row] = f2bf(x.z);
            vt_lds[(colf * 4 + 3) * VTSTRIDE + row] = f2bf(x.w);
        }
        __syncthreads();

        f32x4 s0 = (f32x4){0.f,0.f,0.f,0.f};
        f32x4 s1 = (f32x4){0.f,0.f,0.f,0.f};
        #pragma unroll
        for (int kt = 0; kt < 4; ++kt) {
            bf16x8 kf0 = *(const bf16x8*)&k_lds[(r16)      * KSTRIDE + 32 * kt + 8 * g];
            bf16x8 kf1 = *(const bf16x8*)&k_lds[(16 + r16) * KSTRIDE + 32 * kt + 8 * g];
            s0 = __builtin_amdgcn_mfma_f32_16x16x32_bf16(qf[kt], kf0, s0, 0, 0, 0);
            s1 = __builtin_amdgcn_mfma_f32_16x16x32_bf16(qf[kt], kf1, s1, 0, 0, 0);
        }

        float alpha[4];
        f32x4 p0, p1;
        #pragma unroll
        for (int r = 0; r < 4; ++r) {
            float t = fmaxf(s0[r], s1[r]);
            t = fmaxf(t, __shfl_xor(t, 1));
            t = fmaxf(t, __shfl_xor(t, 2));
            t = fmaxf(t, __shfl_xor(t, 4));
            t = fmaxf(t, __shfl_xor(t, 8));
            float mn = fmaxf(m_run[r], t);
            alpha[r] = __expf(m_run[r] - mn);
            m_run[r] = mn;
            p0[r] = __expf(s0[r] - mn);
            p1[r] = __expf(s1[r] - mn);
            float su = p0[r] + p1[r];
            su += __shfl_xor(su, 1);
            su += __shfl_xor(su, 2);
            su += __shfl_xor(su, 4);
            su += __shfl_xor(su, 8);
            l_run[r] = l_run[r] * alpha[r] + su;
        }

        unsigned short* pw = &p_lds2[wave * 16 * VTSTRIDE];
        #pragma unroll
        for (int r = 0; r < 4; ++r) {
            int row = 4 * g + r;
            pw[row * VTSTRIDE + r16]      = f2bf(p0[r]);
            pw[row * VTSTRIDE + 16 + r16] = f2bf(p1[r]);
        }
        bf16x8 pf = *(const bf16x8*)&pw[r16 * VTSTRIDE + 8 * g];

        #pragma unroll
        for (int dt = 0; dt < 8; ++dt) {
            #pragma unroll
            for (int r = 0; r < 4; ++r) o_acc[dt][r] *= alpha[r];
        }
        #pragma unroll
        for (int dt = 0; dt < 8; ++dt) {
            bf16x8 vf = *(const bf16x8*)&vt_lds[(16 * dt + r16) * VTSTRIDE + 8 * g];
            o_acc[dt] = __builtin_amdgcn_mfma_f32_16x16x32_bf16(pf, vf, o_acc[dt], 0, 0, 0);
        }
    }

    #pragma unroll
    for (int r = 0; r < 4; ++r) {
        float inv = 1.0f / l_run[r];
        int row = qb * 64 + wave * 16 + 4 * g + r;
        float* op = Oh + (size_t)row * DD + r16;
        #pragma unroll
        for (int dt = 0; dt < 8; ++dt)
            op[16 * dt] = o_acc[dt][r] * inv;
    }
}

extern "C" void kernel_launch(void* const* d_in, const int* in_sizes, int n_in,
                              void* d_out, int out_size, void* d_ws, size_t ws_size,
                              hipStream_t stream) {
    const float* q = (const float*)d_in[0];
    const float* k = (const float*)d_in[1];
    const float* v = (const float*)d_in[2];
    float* o = (float*)d_out;

    hipError_t attr_ok = hipFuncSetAttribute(
        (const void*)attn_main_kernel,
        hipFuncAttributeMaxDynamicSharedMemorySize, SMEM_MAIN);

    if (ws_size >= WS_NEED && attr_ok == hipSuccess) {
        char* ws = (char*)d_ws;
        prep_kv_kernel<<<dim3(NKV, NHEADS), 256, 0, stream>>>(k, v, ws);
        attn_main_kernel<<<dim3(NQB * NHEADS), 512, SMEM_MAIN, stream>>>(
            q, ws, ws + WS_K_BYTES, o);
    } else {
        attn_fwd_fallback<<<dim3(LQ_N / 64, NHEADS), 256, 0, stream>>>(q, k, v, o);
    }
}